// Round 4
// baseline (615.597 us; speedup 1.0000x reference)
//
#include <hip/hip_runtime.h>

#define NN 8192
#define FIN 512
#define FO 64

typedef __attribute__((ext_vector_type(8))) short short8;
typedef __attribute__((ext_vector_type(16))) float f32x16;
typedef __attribute__((ext_vector_type(4))) unsigned int uintx4;
typedef __attribute__((ext_vector_type(4))) int intv4;
typedef __attribute__((ext_vector_type(4))) float fltv4;
typedef unsigned short u16;
typedef unsigned int u32;
typedef unsigned long long u64;

// bf16 round-to-nearest-even, bits only
__device__ inline u16 f2bf(float x) {
  u32 u = __builtin_bit_cast(u32, x);
  return (u16)((u + 0x7FFFu + ((u >> 16) & 1u)) >> 16);
}

// pack two floats to bf16x2 (RNE); accumulate the ROUNDED values into sum
__device__ inline u32 bfpack2(float a, float b, float& sum) {
  u32 ua = __builtin_bit_cast(u32, a);
  u32 ub = __builtin_bit_cast(u32, b);
  ua += 0x7FFFu + ((ua >> 16) & 1u);
  ub += 0x7FFFu + ((ub >> 16) & 1u);
  sum += __builtin_bit_cast(float, ua & 0xFFFF0000u);
  sum += __builtin_bit_cast(float, ub & 0xFFFF0000u);
  return (ua >> 16) | (ub & 0xFFFF0000u);
}

// ---------------- Kernel 1: Wh = h@W (fp32), s = Wh@a1, v = Wh@a2, Whb = bf16(Wh)
// block 256: 16 rows x 16 f-quads. grid 512.
__global__ __launch_bounds__(256) void k1_wh(const float* __restrict__ h,
    const float* __restrict__ W, const float* __restrict__ a,
    float* __restrict__ s, float* __restrict__ v, u16* __restrict__ whb) {
  int tid = threadIdx.x;
  int row = blockIdx.x * 16 + (tid >> 4);
  int fq = (tid & 15) << 2;
  const float* hr = h + (size_t)row * FIN;
  float ax = 0.f, ay = 0.f, az = 0.f, aw = 0.f;
  #pragma unroll 4
  for (int k = 0; k < FIN; k += 4) {
    float4 h4 = *(const float4*)(hr + k);
    float4 w0 = *(const float4*)(W + (size_t)(k + 0) * FO + fq);
    float4 w1 = *(const float4*)(W + (size_t)(k + 1) * FO + fq);
    float4 w2 = *(const float4*)(W + (size_t)(k + 2) * FO + fq);
    float4 w3 = *(const float4*)(W + (size_t)(k + 3) * FO + fq);
    ax += h4.x * w0.x + h4.y * w1.x + h4.z * w2.x + h4.w * w3.x;
    ay += h4.x * w0.y + h4.y * w1.y + h4.z * w2.y + h4.w * w3.y;
    az += h4.x * w0.z + h4.y * w1.z + h4.z * w2.z + h4.w * w3.z;
    aw += h4.x * w0.w + h4.y * w1.w + h4.z * w2.w + h4.w * w3.w;
  }
  ushort4 st4;
  st4.x = f2bf(ax); st4.y = f2bf(ay); st4.z = f2bf(az); st4.w = f2bf(aw);
  *(ushort4*)(whb + (size_t)row * FO + fq) = st4;
  float4 a1 = *(const float4*)(a + fq);
  float4 a2 = *(const float4*)(a + FO + fq);
  float sp = ax * a1.x + ay * a1.y + az * a1.z + aw * a1.w;
  float vp = ax * a2.x + ay * a2.y + az * a2.z + aw * a2.w;
  #pragma unroll
  for (int d = 1; d < 16; d <<= 1) { sp += __shfl_xor(sp, d); vp += __shfl_xor(vp, d); }
  if ((tid & 15) == 0) { s[row] = sp; v[row] = vp; }
}

// ---------------- Kernel 1b: Bpack = Whb rearranged into exact MFMA B-fragment order.
// frag (ks, t): lane l holds B[k = ks*16 + (l>>5)*8 + r][n = t*32 + (l&31)], 1KB per frag.
// block 256 handles 64 j-rows (= 4 ksteps). grid 128.
__global__ __launch_bounds__(256) void k1b_pack(const u16* __restrict__ whb,
                                               u16* __restrict__ bpack) {
  __shared__ __attribute__((aligned(16))) u16 ld[64 * 64];
  int tid = threadIdx.x;
  const uint4* src = (const uint4*)(whb + (size_t)blockIdx.x * 64 * 64);
  uint4* dst = (uint4*)ld;
  dst[tid] = src[tid];
  dst[tid + 256] = src[tid + 256];
  __syncthreads();
  int lane = tid & 63;
  int w = tid >> 6;                 // kstep local 0..3
  int ks = blockIdx.x * 4 + w;      // global kstep 0..511
  int m = lane & 31;
  int half = lane >> 5;
  #pragma unroll
  for (int tt = 0; tt < 2; ++tt) {
    u32 o0, o1, o2, o3;
    int krow = w * 16 + half * 8;
    int n = tt * 32 + m;
    o0 = (u32)ld[(krow + 0) * 64 + n] | ((u32)ld[(krow + 1) * 64 + n] << 16);
    o1 = (u32)ld[(krow + 2) * 64 + n] | ((u32)ld[(krow + 3) * 64 + n] << 16);
    o2 = (u32)ld[(krow + 4) * 64 + n] | ((u32)ld[(krow + 5) * 64 + n] << 16);
    o3 = (u32)ld[(krow + 6) * 64 + n] | ((u32)ld[(krow + 7) * 64 + n] << 16);
    uint4 ov; ov.x = o0; ov.y = o1; ov.z = o2; ov.w = o3;
    *(uint4*)(bpack + (((size_t)ks * 2 + tt) * 64 + lane) * 8) = ov;
  }
}

// ---------------- Kernel 2: t = 0.5*(M@v + adj@v); pack adj row bits into bitmap.
// one block per row, 256 threads, nontemporal ext-vector streams. grid 8192.
// bitmap word layout: word = i*128 + (j>>10)*16 + ((j>>8)&3)*4 + (j&3), bit = (j>>2)&63
__global__ __launch_bounds__(256) void k2_hv(const int* __restrict__ adj,
    const float* __restrict__ M, const float* __restrict__ v,
    float* __restrict__ t, u64* __restrict__ bm) {
  int i = blockIdx.x;
  int tid = threadIdx.x;
  int lane = tid & 63;
  int w = tid >> 6;
  const intv4* arow = (const intv4*)(adj + (size_t)i * NN);
  const fltv4* mrow = (const fltv4*)(M + (size_t)i * NN);
  const fltv4* v4 = (const fltv4*)v;
  float acc = 0.f;
  #pragma unroll
  for (int it = 0; it < 8; ++it) {
    int idx = it * 256 + tid;
    intv4 a4 = __builtin_nontemporal_load(arow + idx);    // single-use 256MB stream
    fltv4 m4 = __builtin_nontemporal_load(mrow + idx);    // single-use 256MB stream
    fltv4 vv = v4[idx];                                   // 32KB, keep cached
    acc += m4.x * vv.x + m4.y * vv.y + m4.z * vv.z + m4.w * vv.w;
    acc += (a4.x ? vv.x : 0.f) + (a4.y ? vv.y : 0.f) + (a4.z ? vv.z : 0.f) + (a4.w ? vv.w : 0.f);
    u64 b0 = __ballot(a4.x != 0);
    u64 b1 = __ballot(a4.y != 0);
    u64 b2 = __ballot(a4.z != 0);
    u64 b3 = __ballot(a4.w != 0);
    if (lane == 0) {
      size_t base = (size_t)i * 128 + it * 16 + w * 4;
      bm[base + 0] = b0; bm[base + 1] = b1; bm[base + 2] = b2; bm[base + 3] = b3;
    }
  }
  #pragma unroll
  for (int d = 1; d < 64; d <<= 1) acc += __shfl_xor(acc, d);
  __shared__ float red[4];
  if (lane == 0) red[w] = acc;
  __syncthreads();
  if (tid == 0) t[i] = 0.5f * (red[0] + red[1] + red[2] + red[3]);
}

// ---------------- Kernel 2b: tmax = max(t); F1[j]=exp(t_j-tmax); F2[j]=exp(0.2(t_j-tmax)).
// Single block, 1024 threads. The exp factor tables kill all transcendentals in k3.
__global__ __launch_bounds__(1024) void k2b_prep(const float* __restrict__ t,
    float* __restrict__ f1, float* __restrict__ f2, float* __restrict__ tmaxg) {
  __shared__ float red[16];
  int tid = threadIdx.x;
  const fltv4* t4 = (const fltv4*)t;
  fltv4 a = t4[tid];
  fltv4 b = t4[tid + 1024];
  float lm = fmaxf(fmaxf(fmaxf(a.x, a.y), fmaxf(a.z, a.w)),
                   fmaxf(fmaxf(b.x, b.y), fmaxf(b.z, b.w)));
  #pragma unroll
  for (int d = 1; d < 64; d <<= 1) lm = fmaxf(lm, __shfl_xor(lm, d));
  if ((tid & 63) == 0) red[tid >> 6] = lm;
  __syncthreads();
  float tmax = red[0];
  #pragma unroll
  for (int r = 1; r < 16; ++r) tmax = fmaxf(tmax, red[r]);
  if (tid == 0) tmaxg[0] = tmax;
  fltv4 o;
  o.x = __expf(a.x - tmax); o.y = __expf(a.y - tmax);
  o.z = __expf(a.z - tmax); o.w = __expf(a.w - tmax);
  ((fltv4*)f1)[tid] = o;
  o.x = __expf(b.x - tmax); o.y = __expf(b.y - tmax);
  o.z = __expf(b.z - tmax); o.w = __expf(b.w - tmax);
  ((fltv4*)f1)[tid + 1024] = o;
  o.x = __expf(0.2f * (a.x - tmax)); o.y = __expf(0.2f * (a.y - tmax));
  o.z = __expf(0.2f * (a.z - tmax)); o.w = __expf(0.2f * (a.w - tmax));
  ((fltv4*)f2)[tid] = o;
  o.x = __expf(0.2f * (b.x - tmax)); o.y = __expf(0.2f * (b.y - tmax));
  o.z = __expf(0.2f * (b.z - tmax)); o.w = __expf(0.2f * (b.w - tmax));
  ((fltv4*)f2)[tid + 1024] = o;
}

// ---------------- Kernel 3: out = elu( softmax-weighted Wh )
// block = 256 (4 waves) handles 32 rows; loops j in tiles of 256.
// weight_ij = adj ? (s_i+t_j>=0 ? E1_i*F1_j : E2_i*F2_j) : 0 — factorized exp,
// zero transcendentals in the hot loop. mx_i = lrelu(s_i + tmax) (shift-invariant bound).
__device__ inline void stage_tile(const u16* __restrict__ bpack, u16* dstbase,
                                  int jt, int w, int lane) {
  const char* g0 = (const char*)bpack + (size_t)jt * 32768 + (size_t)lane * 16;
  #pragma unroll
  for (int cc = 0; cc < 8; ++cc) {
    int chunk = w * 8 + cc;
    const void* gp = g0 + chunk * 1024;
    void* lp = (char*)dstbase + chunk * 1024;
    __builtin_amdgcn_global_load_lds((const __attribute__((address_space(1))) u32*)gp,
                                     (__attribute__((address_space(3))) u32*)lp, 16, 0, 0);
  }
}

__global__ __launch_bounds__(256) void k3_att(const u16* __restrict__ bpack,
    const u64* __restrict__ bm, const float* __restrict__ t,
    const float* __restrict__ f1, const float* __restrict__ f2,
    const float* __restrict__ s, const float* __restrict__ tmaxg,
    float* __restrict__ out) {
  __shared__ __attribute__((aligned(16))) u16 bbuf[2][16384];   // 2 x 32KB
  __shared__ __attribute__((aligned(16))) float accbuf[4 * 2 * 64 * 16]; // 32KB
  __shared__ float zbuf[4][64];
  int tid = threadIdx.x;
  int lane = tid & 63;
  int w = tid >> 6;
  int m = lane & 31;
  int half = lane >> 5;
  int i0 = blockIdx.x << 5;
  int row = i0 + m;
  stage_tile(bpack, bbuf[0], 0, w, lane);
  float srow = s[row];
  float tmax = tmaxg[0];
  float um = srow + tmax;
  float mxv = fmaxf(um, 0.2f * um);
  float E1 = __expf(um - mxv);           // <= 1
  float E2 = __expf(0.2f * um - mxv);    // <= 1
  float negs = -srow;                    // branch: t_j >= -s_i

  f32x16 acc0, acc1;
  #pragma unroll
  for (int r = 0; r < 16; ++r) { acc0[r] = 0.f; acc1[r] = 0.f; }
  float zpart = 0.f;
  int cur = 0;
  for (int jt = 0; jt < 32; ++jt) {
    __syncthreads();                       // tile jt resident in bbuf[cur]
    if (jt + 1 < 32) stage_tile(bpack, bbuf[cur ^ 1], jt + 1, w, lane);
    // 4 bitmap words cover this wave's 64-j span of the tile
    const u64* wp = bm + (size_t)row * 128 + ((jt >> 2) << 4) + ((jt & 3) << 2);
    u64 wd0 = wp[0], wd1 = wp[1], wd2 = wp[2], wd3 = wp[3];
    int off = (jt << 8) + (w << 6) + (half << 3);
    const float* tb = t + off;
    const float* p1 = f1 + off;
    const float* p2 = f2 + off;
    #pragma unroll
    for (int c = 0; c < 4; ++c) {
      int ks = (w << 2) + c;               // kstep-local 0..15
      float4 t0 = *(const float4*)(tb + (c << 4));
      float4 t1 = *(const float4*)(tb + (c << 4) + 4);
      float4 A0 = *(const float4*)(p1 + (c << 4));
      float4 A1 = *(const float4*)(p1 + (c << 4) + 4);
      float4 B0 = *(const float4*)(p2 + (c << 4));
      float4 B1 = *(const float4*)(p2 + (c << 4) + 4);
      int sh = (w << 4) + (c << 2) + (half << 1);
      u32 q0 = (u32)(wd0 >> sh), q1 = (u32)(wd1 >> sh);
      u32 q2 = (u32)(wd2 >> sh), q3 = (u32)(wd3 >> sh);
      float g0 = (t0.x >= negs) ? E1 * A0.x : E2 * B0.x;
      float g1 = (t0.y >= negs) ? E1 * A0.y : E2 * B0.y;
      float g2 = (t0.z >= negs) ? E1 * A0.z : E2 * B0.z;
      float g3 = (t0.w >= negs) ? E1 * A0.w : E2 * B0.w;
      float g4 = (t1.x >= negs) ? E1 * A1.x : E2 * B1.x;
      float g5 = (t1.y >= negs) ? E1 * A1.y : E2 * B1.y;
      float g6 = (t1.z >= negs) ? E1 * A1.z : E2 * B1.z;
      float g7 = (t1.w >= negs) ? E1 * A1.w : E2 * B1.w;
      float w0 = (q0 & 1u) ? g0 : 0.f;
      float w1 = (q1 & 1u) ? g1 : 0.f;
      float w2 = (q2 & 1u) ? g2 : 0.f;
      float w3 = (q3 & 1u) ? g3 : 0.f;
      float w4 = (q0 & 2u) ? g4 : 0.f;
      float w5 = (q1 & 2u) ? g5 : 0.f;
      float w6 = (q2 & 2u) ? g6 : 0.f;
      float w7 = (q3 & 2u) ? g7 : 0.f;
      uintx4 awv;
      awv.x = bfpack2(w0, w1, zpart);
      awv.y = bfpack2(w2, w3, zpart);
      awv.z = bfpack2(w4, w5, zpart);
      awv.w = bfpack2(w6, w7, zpart);
      short8 af = __builtin_bit_cast(short8, awv);
      short8 b0 = *(const short8*)(bbuf[cur] + (((ks << 1) + 0) * 64 + lane) * 8);
      short8 b1 = *(const short8*)(bbuf[cur] + (((ks << 1) + 1) * 64 + lane) * 8);
      acc0 = __builtin_amdgcn_mfma_f32_32x32x16_bf16(af, b0, acc0, 0, 0, 0);
      acc1 = __builtin_amdgcn_mfma_f32_32x32x16_bf16(af, b1, acc1, 0, 0, 0);
    }
    cur ^= 1;
  }
  __syncthreads();
  zbuf[w][lane] = zpart;
  {
    float* ab = accbuf + (((w << 1) + 0) * 64 + lane) * 16;
    #pragma unroll
    for (int r = 0; r < 16; ++r) ab[r] = acc0[r];
    ab = accbuf + (((w << 1) + 1) * 64 + lane) * 16;
    #pragma unroll
    for (int r = 0; r < 16; ++r) ab[r] = acc1[r];
  }
  __syncthreads();
  int mm = tid >> 3;
  int fb = (tid & 7) << 3;
  float zr = 0.f;
  #pragma unroll
  for (int ww = 0; ww < 4; ++ww) zr += zbuf[ww][mm] + zbuf[ww][mm + 32];
  float inv = 1.f / zr;
  int reg = (mm & 3) + ((mm >> 3) << 2);   // C/D: row = (reg&3) + 8*(reg>>2) + 4*(lane>>5)
  int h2 = (mm >> 2) & 1;
  #pragma unroll
  for (int ff = 0; ff < 8; ++ff) {
    int f = fb + ff;
    int tt = f >> 5;
    int col = f & 31;
    float val = 0.f;
    #pragma unroll
    for (int ww = 0; ww < 4; ++ww)
      val += accbuf[(((ww << 1) + tt) * 64 + col + (h2 << 5)) * 16 + reg];
    float o = val * inv;
    out[((size_t)(i0 + mm) << 6) + f] = o > 0.f ? o : (__expf(o) - 1.f);
  }
}

extern "C" void kernel_launch(void* const* d_in, const int* in_sizes, int n_in,
                              void* d_out, int out_size, void* d_ws, size_t ws_size,
                              hipStream_t stream) {
  const float* h   = (const float*)d_in[0];
  const int*   adj = (const int*)d_in[1];
  const float* M   = (const float*)d_in[2];
  const float* W   = (const float*)d_in[3];
  const float* a   = (const float*)d_in[4];
  float* out = (float*)d_out;
  char* ws = (char*)d_ws;
  u64*  bm    = (u64*)ws;                              // 8 MB  (8192*128 u64)
  u16*  whb   = (u16*)(ws + (8u << 20));               // 1 MB
  u16*  bpack = (u16*)(ws + (9u << 20));               // 1 MB
  float* s    = (float*)(ws + (10u << 20));            // 32 KB
  float* v    = (float*)(ws + (10u << 20) + 32768);    // 32 KB
  float* t    = (float*)(ws + (10u << 20) + 65536);    // 32 KB
  float* f1   = (float*)(ws + (10u << 20) + 98304);    // 32 KB
  float* f2   = (float*)(ws + (10u << 20) + 131072);   // 32 KB
  float* tmx  = (float*)(ws + (10u << 20) + 163840);   // 4 B

  k1_wh   <<<512, 256, 0, stream>>>(h, W, a, s, v, whb);
  k1b_pack<<<128, 256, 0, stream>>>(whb, bpack);
  k2_hv   <<<NN, 256, 0, stream>>>(adj, M, v, t, bm);
  k2b_prep<<<1, 1024, 0, stream>>>(t, f1, f2, tmx);
  k3_att  <<<256, 256, 0, stream>>>(bpack, bm, t, f1, f2, s, tmx, out);
}

// Round 5
// 597.416 us; speedup vs baseline: 1.0304x; 1.0304x over previous
//
#include <hip/hip_runtime.h>

#define NN 8192
#define FIN 512
#define FO 64

typedef __attribute__((ext_vector_type(8))) short short8;
typedef __attribute__((ext_vector_type(16))) float f32x16;
typedef __attribute__((ext_vector_type(4))) unsigned int uintx4;
typedef __attribute__((ext_vector_type(4))) int intv4;
typedef __attribute__((ext_vector_type(4))) float fltv4;
typedef unsigned short u16;
typedef unsigned int u32;
typedef unsigned long long u64;

// bf16 round-to-nearest-even, bits only
__device__ inline u16 f2bf(float x) {
  u32 u = __builtin_bit_cast(u32, x);
  return (u16)((u + 0x7FFFu + ((u >> 16) & 1u)) >> 16);
}

// pack two floats to bf16x2 (RNE); accumulate the ROUNDED values into sum
__device__ inline u32 bfpack2(float a, float b, float& sum) {
  u32 ua = __builtin_bit_cast(u32, a);
  u32 ub = __builtin_bit_cast(u32, b);
  ua += 0x7FFFu + ((ua >> 16) & 1u);
  ub += 0x7FFFu + ((ub >> 16) & 1u);
  sum += __builtin_bit_cast(float, ua & 0xFFFF0000u);
  sum += __builtin_bit_cast(float, ub & 0xFFFF0000u);
  return (ua >> 16) | (ub & 0xFFFF0000u);
}

// ---------------- Kernel 1: Wh = h@W (fp32), s = Wh@a1, v = Wh@a2, Whb = bf16(Wh)
// block 256: 16 rows x 16 f-quads. grid 512.
__global__ __launch_bounds__(256) void k1_wh(const float* __restrict__ h,
    const float* __restrict__ W, const float* __restrict__ a,
    float* __restrict__ s, float* __restrict__ v, u16* __restrict__ whb) {
  int tid = threadIdx.x;
  int row = blockIdx.x * 16 + (tid >> 4);
  int fq = (tid & 15) << 2;
  const float* hr = h + (size_t)row * FIN;
  float ax = 0.f, ay = 0.f, az = 0.f, aw = 0.f;
  #pragma unroll 4
  for (int k = 0; k < FIN; k += 4) {
    float4 h4 = *(const float4*)(hr + k);
    float4 w0 = *(const float4*)(W + (size_t)(k + 0) * FO + fq);
    float4 w1 = *(const float4*)(W + (size_t)(k + 1) * FO + fq);
    float4 w2 = *(const float4*)(W + (size_t)(k + 2) * FO + fq);
    float4 w3 = *(const float4*)(W + (size_t)(k + 3) * FO + fq);
    ax += h4.x * w0.x + h4.y * w1.x + h4.z * w2.x + h4.w * w3.x;
    ay += h4.x * w0.y + h4.y * w1.y + h4.z * w2.y + h4.w * w3.y;
    az += h4.x * w0.z + h4.y * w1.z + h4.z * w2.z + h4.w * w3.z;
    aw += h4.x * w0.w + h4.y * w1.w + h4.z * w2.w + h4.w * w3.w;
  }
  ushort4 st4;
  st4.x = f2bf(ax); st4.y = f2bf(ay); st4.z = f2bf(az); st4.w = f2bf(aw);
  *(ushort4*)(whb + (size_t)row * FO + fq) = st4;
  float4 a1 = *(const float4*)(a + fq);
  float4 a2 = *(const float4*)(a + FO + fq);
  float sp = ax * a1.x + ay * a1.y + az * a1.z + aw * a1.w;
  float vp = ax * a2.x + ay * a2.y + az * a2.z + aw * a2.w;
  #pragma unroll
  for (int d = 1; d < 16; d <<= 1) { sp += __shfl_xor(sp, d); vp += __shfl_xor(vp, d); }
  if ((tid & 15) == 0) { s[row] = sp; v[row] = vp; }
}

// ---------------- Kernel 1b: Bpack = Whb rearranged into exact MFMA B-fragment order.
// frag (ks, t): lane l holds B[k = ks*16 + (l>>5)*8 + r][n = t*32 + (l&31)], 1KB per frag.
// block 256 handles 64 j-rows (= 4 ksteps). grid 128.
__global__ __launch_bounds__(256) void k1b_pack(const u16* __restrict__ whb,
                                               u16* __restrict__ bpack) {
  __shared__ __attribute__((aligned(16))) u16 ld[64 * 64];
  int tid = threadIdx.x;
  const uint4* src = (const uint4*)(whb + (size_t)blockIdx.x * 64 * 64);
  uint4* dst = (uint4*)ld;
  dst[tid] = src[tid];
  dst[tid + 256] = src[tid + 256];
  __syncthreads();
  int lane = tid & 63;
  int w = tid >> 6;                 // kstep local 0..3
  int ks = blockIdx.x * 4 + w;      // global kstep 0..511
  int m = lane & 31;
  int half = lane >> 5;
  #pragma unroll
  for (int tt = 0; tt < 2; ++tt) {
    u32 o0, o1, o2, o3;
    int krow = w * 16 + half * 8;
    int n = tt * 32 + m;
    o0 = (u32)ld[(krow + 0) * 64 + n] | ((u32)ld[(krow + 1) * 64 + n] << 16);
    o1 = (u32)ld[(krow + 2) * 64 + n] | ((u32)ld[(krow + 3) * 64 + n] << 16);
    o2 = (u32)ld[(krow + 4) * 64 + n] | ((u32)ld[(krow + 5) * 64 + n] << 16);
    o3 = (u32)ld[(krow + 6) * 64 + n] | ((u32)ld[(krow + 7) * 64 + n] << 16);
    uint4 ov; ov.x = o0; ov.y = o1; ov.z = o2; ov.w = o3;
    *(uint4*)(bpack + (((size_t)ks * 2 + tt) * 64 + lane) * 8) = ov;
  }
}

// ---------------- Kernel 2: t = 0.5*(M@v + adj@v); pack adj row bits into bitmap.
// one block per row, 256 threads, nontemporal ext-vector streams. grid 8192.
// bitmap word layout: word = i*128 + (j>>10)*16 + ((j>>8)&3)*4 + (j&3), bit = (j>>2)&63
__global__ __launch_bounds__(256) void k2_hv(const int* __restrict__ adj,
    const float* __restrict__ M, const float* __restrict__ v,
    float* __restrict__ t, u64* __restrict__ bm) {
  int i = blockIdx.x;
  int tid = threadIdx.x;
  int lane = tid & 63;
  int w = tid >> 6;
  const intv4* arow = (const intv4*)(adj + (size_t)i * NN);
  const fltv4* mrow = (const fltv4*)(M + (size_t)i * NN);
  const fltv4* v4 = (const fltv4*)v;
  float acc = 0.f;
  #pragma unroll
  for (int it = 0; it < 8; ++it) {
    int idx = it * 256 + tid;
    intv4 a4 = __builtin_nontemporal_load(arow + idx);    // single-use 256MB stream
    fltv4 m4 = __builtin_nontemporal_load(mrow + idx);    // single-use 256MB stream
    fltv4 vv = v4[idx];                                   // 32KB, keep cached
    acc += m4.x * vv.x + m4.y * vv.y + m4.z * vv.z + m4.w * vv.w;
    acc += (a4.x ? vv.x : 0.f) + (a4.y ? vv.y : 0.f) + (a4.z ? vv.z : 0.f) + (a4.w ? vv.w : 0.f);
    u64 b0 = __ballot(a4.x != 0);
    u64 b1 = __ballot(a4.y != 0);
    u64 b2 = __ballot(a4.z != 0);
    u64 b3 = __ballot(a4.w != 0);
    if (lane == 0) {
      size_t base = (size_t)i * 128 + it * 16 + w * 4;
      bm[base + 0] = b0; bm[base + 1] = b1; bm[base + 2] = b2; bm[base + 3] = b3;
    }
  }
  #pragma unroll
  for (int d = 1; d < 64; d <<= 1) acc += __shfl_xor(acc, d);
  __shared__ float red[4];
  if (lane == 0) red[w] = acc;
  __syncthreads();
  if (tid == 0) t[i] = 0.5f * (red[0] + red[1] + red[2] + red[3]);
}

// ---------------- Kernel 3: out = elu( softmax-weighted Wh )
// block = 256 (4 waves) handles 32 rows; loops j in tiles of 256.
// mx_i = lrelu(s_i + max_j t_j): softmax is shift-invariant, any upper bound on the
// row max keeps exp args <= 0; global t-max is computed inline (overlaps prefetch).
// R4 lesson: inner loop is issue/latency-balanced — inline __expf beats factorized
// table loads (exp co-schedules with MFMA; extra VMEM does not).
__device__ inline void stage_tile(const u16* __restrict__ bpack, u16* dstbase,
                                  int jt, int w, int lane) {
  const char* g0 = (const char*)bpack + (size_t)jt * 32768 + (size_t)lane * 16;
  #pragma unroll
  for (int cc = 0; cc < 8; ++cc) {
    int chunk = w * 8 + cc;
    const void* gp = g0 + chunk * 1024;
    void* lp = (char*)dstbase + chunk * 1024;
    __builtin_amdgcn_global_load_lds((const __attribute__((address_space(1))) u32*)gp,
                                     (__attribute__((address_space(3))) u32*)lp, 16, 0, 0);
  }
}

__global__ __launch_bounds__(256) void k3_att(const u16* __restrict__ bpack,
    const u64* __restrict__ bm, const float* __restrict__ t,
    const float* __restrict__ s, float* __restrict__ out) {
  __shared__ __attribute__((aligned(16))) u16 bbuf[2][16384];   // 2 x 32KB
  __shared__ __attribute__((aligned(16))) float accbuf[4 * 2 * 64 * 16]; // 32KB
  __shared__ float zbuf[4][64];
  __shared__ float wred[4];
  int tid = threadIdx.x;
  int lane = tid & 63;
  int w = tid >> 6;
  int m = lane & 31;
  int half = lane >> 5;
  int i0 = blockIdx.x << 5;
  int row = i0 + m;
  float srow = s[row];
  stage_tile(bpack, bbuf[0], 0, w, lane);
  // inline global t-max reduction (overlaps tile-0 prefetch)
  float lmax = -3e38f;
  const float4* t4 = (const float4*)t;
  #pragma unroll
  for (int r = 0; r < 8; ++r) {
    float4 tv = t4[r * 256 + tid];
    lmax = fmaxf(fmaxf(lmax, fmaxf(tv.x, tv.y)), fmaxf(tv.z, tv.w));
  }
  #pragma unroll
  for (int d = 1; d < 64; d <<= 1) lmax = fmaxf(lmax, __shfl_xor(lmax, d));
  if (lane == 0) wred[w] = lmax;
  __syncthreads();
  float tmax = fmaxf(fmaxf(wred[0], wred[1]), fmaxf(wred[2], wred[3]));
  float um = srow + tmax;
  float mxv = fmaxf(um, 0.2f * um);

  f32x16 acc0, acc1;
  #pragma unroll
  for (int r = 0; r < 16; ++r) { acc0[r] = 0.f; acc1[r] = 0.f; }
  float zpart = 0.f;
  int cur = 0;
  for (int jt = 0; jt < 32; ++jt) {
    __syncthreads();                       // tile jt resident in bbuf[cur]
    if (jt + 1 < 32) stage_tile(bpack, bbuf[cur ^ 1], jt + 1, w, lane);
    // 4 bitmap words cover this wave's 64-j span of the tile
    const u64* wp = bm + (size_t)row * 128 + ((jt >> 2) << 4) + ((jt & 3) << 2);
    u64 wd0 = wp[0], wd1 = wp[1], wd2 = wp[2], wd3 = wp[3];
    const float* tb = t + (jt << 8) + (w << 6) + (half << 3);
    #pragma unroll
    for (int c = 0; c < 4; ++c) {
      int ks = (w << 2) + c;               // kstep-local 0..15
      float4 t0 = *(const float4*)(tb + (c << 4));
      float4 t1 = *(const float4*)(tb + (c << 4) + 4);
      int sh = (w << 4) + (c << 2) + (half << 1);
      u32 q0 = (u32)(wd0 >> sh), q1 = (u32)(wd1 >> sh);
      u32 q2 = (u32)(wd2 >> sh), q3 = (u32)(wd3 >> sh);
      float u0 = srow + t0.x, u1 = srow + t0.y, u2 = srow + t0.z, u3 = srow + t0.w;
      float u4 = srow + t1.x, u5 = srow + t1.y, u6 = srow + t1.z, u7 = srow + t1.w;
      float g0 = __expf(fmaxf(u0, 0.2f * u0) - mxv);
      float g1 = __expf(fmaxf(u1, 0.2f * u1) - mxv);
      float g2 = __expf(fmaxf(u2, 0.2f * u2) - mxv);
      float g3 = __expf(fmaxf(u3, 0.2f * u3) - mxv);
      float g4 = __expf(fmaxf(u4, 0.2f * u4) - mxv);
      float g5 = __expf(fmaxf(u5, 0.2f * u5) - mxv);
      float g6 = __expf(fmaxf(u6, 0.2f * u6) - mxv);
      float g7 = __expf(fmaxf(u7, 0.2f * u7) - mxv);
      float w0 = (q0 & 1u) ? g0 : 0.f;
      float w1 = (q1 & 1u) ? g1 : 0.f;
      float w2 = (q2 & 1u) ? g2 : 0.f;
      float w3 = (q3 & 1u) ? g3 : 0.f;
      float w4 = (q0 & 2u) ? g4 : 0.f;
      float w5 = (q1 & 2u) ? g5 : 0.f;
      float w6 = (q2 & 2u) ? g6 : 0.f;
      float w7 = (q3 & 2u) ? g7 : 0.f;
      uintx4 awv;
      awv.x = bfpack2(w0, w1, zpart);
      awv.y = bfpack2(w2, w3, zpart);
      awv.z = bfpack2(w4, w5, zpart);
      awv.w = bfpack2(w6, w7, zpart);
      short8 af = __builtin_bit_cast(short8, awv);
      short8 b0 = *(const short8*)(bbuf[cur] + (((ks << 1) + 0) * 64 + lane) * 8);
      short8 b1 = *(const short8*)(bbuf[cur] + (((ks << 1) + 1) * 64 + lane) * 8);
      acc0 = __builtin_amdgcn_mfma_f32_32x32x16_bf16(af, b0, acc0, 0, 0, 0);
      acc1 = __builtin_amdgcn_mfma_f32_32x32x16_bf16(af, b1, acc1, 0, 0, 0);
    }
    cur ^= 1;
  }
  __syncthreads();
  zbuf[w][lane] = zpart;
  {
    float* ab = accbuf + (((w << 1) + 0) * 64 + lane) * 16;
    #pragma unroll
    for (int r = 0; r < 16; ++r) ab[r] = acc0[r];
    ab = accbuf + (((w << 1) + 1) * 64 + lane) * 16;
    #pragma unroll
    for (int r = 0; r < 16; ++r) ab[r] = acc1[r];
  }
  __syncthreads();
  int mm = tid >> 3;
  int fb = (tid & 7) << 3;
  float zr = 0.f;
  #pragma unroll
  for (int ww = 0; ww < 4; ++ww) zr += zbuf[ww][mm] + zbuf[ww][mm + 32];
  float inv = 1.f / zr;
  int reg = (mm & 3) + ((mm >> 3) << 2);   // C/D: row = (reg&3) + 8*(reg>>2) + 4*(lane>>5)
  int h2 = (mm >> 2) & 1;
  #pragma unroll
  for (int ff = 0; ff < 8; ++ff) {
    int f = fb + ff;
    int tt = f >> 5;
    int col = f & 31;
    float val = 0.f;
    #pragma unroll
    for (int ww = 0; ww < 4; ++ww)
      val += accbuf[(((ww << 1) + tt) * 64 + col + (h2 << 5)) * 16 + reg];
    float o = val * inv;
    out[((size_t)(i0 + mm) << 6) + f] = o > 0.f ? o : (__expf(o) - 1.f);
  }
}

extern "C" void kernel_launch(void* const* d_in, const int* in_sizes, int n_in,
                              void* d_out, int out_size, void* d_ws, size_t ws_size,
                              hipStream_t stream) {
  const float* h   = (const float*)d_in[0];
  const int*   adj = (const int*)d_in[1];
  const float* M   = (const float*)d_in[2];
  const float* W   = (const float*)d_in[3];
  const float* a   = (const float*)d_in[4];
  float* out = (float*)d_out;
  char* ws = (char*)d_ws;
  u64*  bm    = (u64*)ws;                              // 8 MB  (8192*128 u64)
  u16*  whb   = (u16*)(ws + (8u << 20));               // 1 MB
  u16*  bpack = (u16*)(ws + (9u << 20));               // 1 MB
  float* s    = (float*)(ws + (10u << 20));            // 32 KB
  float* v    = (float*)(ws + (10u << 20) + 32768);    // 32 KB
  float* t    = (float*)(ws + (10u << 20) + 65536);    // 32 KB

  k1_wh  <<<512, 256, 0, stream>>>(h, W, a, s, v, whb);
  k1b_pack<<<128, 256, 0, stream>>>(whb, bpack);
  k2_hv  <<<NN, 256, 0, stream>>>(adj, M, v, t, bm);
  k3_att <<<256, 256, 0, stream>>>(bpack, bm, t, s, out);
}